// Round 11
// baseline (204.826 us; speedup 1.0000x reference)
//
#include <hip/hip_runtime.h>
#include <math.h>

#define NB 8
#define NL 4096
#define ND 2048
#define NE 8
#define KTOP 2
#define NR 8
#define ALPHA 0.125f
#define LN_EPS 1e-5f
#define SPLIT 64

typedef float f32x4 __attribute__((ext_vector_type(4)));

// ---------------- k1: partial sums of x over L chunks -> partial[b][s][D]
// grid: SPLIT * NB * 2 halves = 1024 blocks. 8 independent accumulators
// (8 HBM loads in flight per wave). At read roofline (~6.3 TB/s) - unchanged.
__global__ __launch_bounds__(256) void k1_partial_mean(const float* __restrict__ x,
                                                       float* __restrict__ partial) {
    int bid = blockIdx.x;
    int half = bid & 1;
    int b = (bid >> 1) & (NB - 1);
    int s = bid >> 4;
    const int lchunk = NL / SPLIT;     // 64
    int d4 = half * 1024 + threadIdx.x * 4;
    const float* xp = x + ((size_t)(b * NL + s * lchunk)) * ND + d4;
    f32x4 a0 = {0.f, 0.f, 0.f, 0.f}, a1 = a0, a2 = a0, a3 = a0;
    f32x4 a4 = a0, a5 = a0, a6 = a0, a7 = a0;
    for (int i = 0; i < lchunk; i += 8) {
        f32x4 v0 = *(const f32x4*)(xp + (size_t)(i + 0) * ND);
        f32x4 v1 = *(const f32x4*)(xp + (size_t)(i + 1) * ND);
        f32x4 v2 = *(const f32x4*)(xp + (size_t)(i + 2) * ND);
        f32x4 v3 = *(const f32x4*)(xp + (size_t)(i + 3) * ND);
        f32x4 v4 = *(const f32x4*)(xp + (size_t)(i + 4) * ND);
        f32x4 v5 = *(const f32x4*)(xp + (size_t)(i + 5) * ND);
        f32x4 v6 = *(const f32x4*)(xp + (size_t)(i + 6) * ND);
        f32x4 v7 = *(const f32x4*)(xp + (size_t)(i + 7) * ND);
        a0 += v0; a1 += v1; a2 += v2; a3 += v3;
        a4 += v4; a5 += v5; a6 += v6; a7 += v7;
    }
    f32x4 acc = ((a0 + a1) + (a2 + a3)) + ((a4 + a5) + (a6 + a7));
    *(f32x4*)(partial + ((size_t)(b * SPLIT + s)) * ND + d4) = acc;
}

// ---------------- kB: reduce partial -> h, router logits, top-2, LoRA delta.
__global__ __launch_bounds__(256) void kB_router(const float* __restrict__ partial,
                                                 const float* __restrict__ gate_w,
                                                 const float* __restrict__ gate_b,
                                                 const float* __restrict__ A,
                                                 const float* __restrict__ Bw,
                                                 float* __restrict__ delta,
                                                 float* __restrict__ logits_out,
                                                 int* __restrict__ idx_out) {
    __shared__ float sh_h[ND];
    __shared__ float sh_logits[NE];
    __shared__ float sh_t[KTOP * NR];
    __shared__ float sh_w[KTOP];
    __shared__ int sh_idx[KTOP];
    int b = blockIdx.x;
    int tid = threadIdx.x;

    const float* pb = partial + (size_t)b * SPLIT * ND;
    for (int d4 = tid; d4 < ND / 4; d4 += 256) {
        f32x4 s0 = {0.f, 0.f, 0.f, 0.f}, s1 = s0, s2 = s0, s3 = s0;
#pragma unroll 4
        for (int s = 0; s < SPLIT; s += 4) {
            s0 += *(const f32x4*)(pb + (size_t)(s + 0) * ND + d4 * 4);
            s1 += *(const f32x4*)(pb + (size_t)(s + 1) * ND + d4 * 4);
            s2 += *(const f32x4*)(pb + (size_t)(s + 2) * ND + d4 * 4);
            s3 += *(const f32x4*)(pb + (size_t)(s + 3) * ND + d4 * 4);
        }
        f32x4 r = ((s0 + s1) + (s2 + s3)) * (1.0f / NL);
        *(f32x4*)(sh_h + d4 * 4) = r;
    }
    __syncthreads();

    {
        int e = tid >> 5, lane32 = tid & 31;
        const f32x4* gw = (const f32x4*)(gate_w + (size_t)e * ND);
        float p = 0.f;
#pragma unroll 4
        for (int d4 = lane32; d4 < ND / 4; d4 += 32) {
            f32x4 gv = gw[d4];
            f32x4 hv = *(const f32x4*)(sh_h + d4 * 4);
            p += gv.x * hv.x + gv.y * hv.y + gv.z * hv.z + gv.w * hv.w;
        }
        for (int off = 16; off; off >>= 1) p += __shfl_down(p, off);
        if (lane32 == 0) sh_logits[e] = p + gate_b[e];
    }
    __syncthreads();

    if (tid == 0) {
        float v1 = -1e30f; int e1 = 0;
        for (int e = 0; e < NE; ++e) if (sh_logits[e] > v1) { v1 = sh_logits[e]; e1 = e; }
        float v2 = -1e30f; int e2 = 0;
        for (int e = 0; e < NE; ++e) if (e != e1 && sh_logits[e] > v2) { v2 = sh_logits[e]; e2 = e; }
        float ex = expf(v2 - v1);
        float w1 = 1.0f / (1.0f + ex);
        sh_idx[0] = e1; sh_idx[1] = e2;
        sh_w[0] = w1; sh_w[1] = ex * w1;
        idx_out[b * KTOP] = e1; idx_out[b * KTOP + 1] = e2;
        for (int e = 0; e < NE; ++e) logits_out[b * NE + e] = sh_logits[e];
    }
    __syncthreads();

    {
        int grp = tid >> 4, lane16 = tid & 15;
        int k = grp >> 3, r = grp & 7;
        int e = sh_idx[k];
        const f32x4* ap = (const f32x4*)(A + ((size_t)e * NR + r) * ND);
        float p = 0.f;
#pragma unroll 4
        for (int d4 = lane16; d4 < ND / 4; d4 += 16) {
            f32x4 av = ap[d4];
            f32x4 hv = *(const f32x4*)(sh_h + d4 * 4);
            p += av.x * hv.x + av.y * hv.y + av.z * hv.z + av.w * hv.w;
        }
        for (int off = 8; off; off >>= 1) p += __shfl_down(p, off);
        if (lane16 == 0) sh_t[grp] = p;
    }
    __syncthreads();

    for (int dd = tid; dd < ND; dd += 256) {
        float acc = 0.f;
#pragma unroll
        for (int k = 0; k < KTOP; ++k) {
            int e = sh_idx[k];
            const f32x4* bw = (const f32x4*)(Bw + ((size_t)e * ND + dd) * NR);
            f32x4 w0 = bw[0], w1 = bw[1];
            float s = sh_t[k * NR + 0] * w0.x + sh_t[k * NR + 1] * w0.y +
                      sh_t[k * NR + 2] * w0.z + sh_t[k * NR + 3] * w0.w +
                      sh_t[k * NR + 4] * w1.x + sh_t[k * NR + 5] * w1.y +
                      sh_t[k * NR + 6] * w1.z + sh_t[k * NR + 7] * w1.w;
            acc += sh_w[k] * s;
        }
        delta[b * ND + dd] = acc * ALPHA;
    }
}

// ---------------- k4: residual + LayerNorm. ONE WAVE = TWO ROWS (row, row+16384).
// A/B cell test: NT x LOADS (x never reused -> don't allocate in L2) +
// NORMAL y stores (give y the full L2 as a combining write buffer -- the
// 7 TB/s fill path). R9 failed with normal loads+stores; if the failure was
// x-allocation starving y's write buffering, this cell wins. If it was y
// write-allocation thrashing the x stream, this regresses and NT-store ~152
// is the roofline.
__global__ __launch_bounds__(256) void k4_ln(const float* __restrict__ x,
                                             const float* __restrict__ delta,
                                             const float* __restrict__ gamma,
                                             const float* __restrict__ beta,
                                             const float* __restrict__ logits,
                                             const int* __restrict__ idxp,
                                             float* __restrict__ y,
                                             float* __restrict__ aux_out) {
    int wave = blockIdx.x * 4 + (threadIdx.x >> 6);   // 0..16383
    int lane = threadIdx.x & 63;
    size_t ra = (size_t)wave * ND;
    size_t rb = ((size_t)wave + 16384) * ND;
    int ba = wave >> 12;            // 0..3
    int bb = ba + 4;

    const f32x4* xa = (const f32x4*)(x + ra);
    const f32x4* xb = (const f32x4*)(x + rb);
    const f32x4* da = (const f32x4*)(delta + (size_t)ba * ND);
    const f32x4* db = (const f32x4*)(delta + (size_t)bb * ND);

    f32x4 va[8], vb[8];
#pragma unroll
    for (int j = 0; j < 8; ++j) va[j] = __builtin_nontemporal_load(xa + lane + 64 * j);
#pragma unroll
    for (int j = 0; j < 8; ++j) vb[j] = __builtin_nontemporal_load(xb + lane + 64 * j);
#pragma unroll
    for (int j = 0; j < 8; ++j) va[j] += da[lane + 64 * j];
#pragma unroll
    for (int j = 0; j < 8; ++j) vb[j] += db[lane + 64 * j];

    float sa = 0.f, ssa = 0.f, sb = 0.f, ssb = 0.f;
#pragma unroll
    for (int j = 0; j < 8; ++j) {
        sa  += va[j].x + va[j].y + va[j].z + va[j].w;
        ssa += va[j].x * va[j].x + va[j].y * va[j].y + va[j].z * va[j].z + va[j].w * va[j].w;
        sb  += vb[j].x + vb[j].y + vb[j].z + vb[j].w;
        ssb += vb[j].x * vb[j].x + vb[j].y * vb[j].y + vb[j].z * vb[j].z + vb[j].w * vb[j].w;
    }
    for (int off = 32; off; off >>= 1) {
        sa  += __shfl_xor(sa, off);
        ssa += __shfl_xor(ssa, off);
        sb  += __shfl_xor(sb, off);
        ssb += __shfl_xor(ssb, off);
    }
    float mua = sa * (1.0f / ND);
    float rsa = rsqrtf(ssa * (1.0f / ND) - mua * mua + LN_EPS);
    float mub = sb * (1.0f / ND);
    float rsb = rsqrtf(ssb * (1.0f / ND) - mub * mub + LN_EPS);

    f32x4* ya = (f32x4*)(y + ra);
    f32x4* yb = (f32x4*)(y + rb);
#pragma unroll
    for (int j = 0; j < 8; ++j) {
        f32x4 gv = *(const f32x4*)(gamma + (lane + 64 * j) * 4);
        f32x4 bv = *(const f32x4*)(beta  + (lane + 64 * j) * 4);
        ya[lane + 64 * j] = (va[j] - mua) * rsa * gv + bv;
        yb[lane + 64 * j] = (vb[j] - mub) * rsb * gv + bv;
    }

    // ---- aux losses (one scalar lane) ----
    if (blockIdx.x == 0 && threadIdx.x == 0) {
        float counts[NE];
        for (int e = 0; e < NE; ++e) counts[e] = 0.f;
        for (int i = 0; i < NB * KTOP; ++i) counts[idxp[i]] += 1.f;
        float f[NE], P[NE];
        for (int e = 0; e < NE; ++e) { f[e] = counts[e] * (1.0f / (NB * KTOP)); P[e] = 0.f; }
        float z = 0.f;
        for (int bq = 0; bq < NB; ++bq) {
            const float* lg = logits + bq * NE;
            float m = lg[0];
            for (int e = 1; e < NE; ++e) m = fmaxf(m, lg[e]);
            float sum = 0.f;
            for (int e = 0; e < NE; ++e) sum += expf(lg[e] - m);
            float inv = 1.0f / sum;
            for (int e = 0; e < NE; ++e) P[e] += expf(lg[e] - m) * inv;
            float lse = m + logf(sum);
            z += lse * lse;
        }
        z *= (1.0f / NB);
        float lb = 0.f;
        for (int e = 0; e < NE; ++e) lb += f[e] * (P[e] * (1.0f / NB));
        lb *= (float)NE;
        float psum = 0.f;
        for (int e = 0; e < NE; ++e) psum += f[e] + 1e-8f;
        float s2 = 0.f;
        for (int e = 0; e < NE; ++e) { float p = (f[e] + 1e-8f) / psum; s2 += p * p; }
        aux_out[0] = 0.01f * lb + 0.001f * z + 0.01f * logf(s2);
    }
}

extern "C" void kernel_launch(void* const* d_in, const int* in_sizes, int n_in,
                              void* d_out, int out_size, void* d_ws, size_t ws_size,
                              hipStream_t stream) {
    const float* x      = (const float*)d_in[0];
    const float* gate_w = (const float*)d_in[1];
    const float* gate_b = (const float*)d_in[2];
    const float* A      = (const float*)d_in[3];
    const float* Bw     = (const float*)d_in[4];
    const float* gamma  = (const float*)d_in[5];
    const float* beta   = (const float*)d_in[6];
    float* y   = (float*)d_out;
    float* aux = y + (size_t)NB * NL * ND;

    // workspace: partial[B][SPLIT][D] | delta[B][D] | logits[B][E] | idx[B][K]
    float* partial = (float*)d_ws;
    float* delta   = partial + (size_t)NB * SPLIT * ND;
    float* logits  = delta + NB * ND;
    int*   idxp    = (int*)(logits + NB * NE);

    hipLaunchKernelGGL(k1_partial_mean, dim3(SPLIT * NB * 2), dim3(256), 0, stream,
                       x, partial);
    hipLaunchKernelGGL(kB_router, dim3(NB), dim3(256), 0, stream,
                       partial, gate_w, gate_b, A, Bw, delta, logits, idxp);
    hipLaunchKernelGGL(k4_ln, dim3(4096), dim3(256), 0, stream,
                       x, delta, gamma, beta, logits, idxp, y, aux);
}

// Round 12
// 145.909 us; speedup vs baseline: 1.4038x; 1.4038x over previous
//
#include <hip/hip_runtime.h>
#include <math.h>

#define NB 8
#define NL 4096
#define ND 2048
#define NE 8
#define KTOP 2
#define NR 8
#define ALPHA 0.125f
#define LN_EPS 1e-5f
#define SPLIT 64

typedef float f32x4 __attribute__((ext_vector_type(4)));

// ---------------- k1: partial sums of x over L chunks -> partial[b][s][D]
// 1024 blocks, 8 accumulators; at read roofline (~6.3 TB/s).
__global__ __launch_bounds__(256) void k1_partial_mean(const float* __restrict__ x,
                                                       float* __restrict__ partial) {
    int bid = blockIdx.x;
    int half = bid & 1;
    int b = (bid >> 1) & (NB - 1);
    int s = bid >> 4;
    const int lchunk = NL / SPLIT;     // 64
    int d4 = half * 1024 + threadIdx.x * 4;
    const float* xp = x + ((size_t)(b * NL + s * lchunk)) * ND + d4;
    f32x4 a0 = {0.f, 0.f, 0.f, 0.f}, a1 = a0, a2 = a0, a3 = a0;
    f32x4 a4 = a0, a5 = a0, a6 = a0, a7 = a0;
    for (int i = 0; i < lchunk; i += 8) {
        f32x4 v0 = *(const f32x4*)(xp + (size_t)(i + 0) * ND);
        f32x4 v1 = *(const f32x4*)(xp + (size_t)(i + 1) * ND);
        f32x4 v2 = *(const f32x4*)(xp + (size_t)(i + 2) * ND);
        f32x4 v3 = *(const f32x4*)(xp + (size_t)(i + 3) * ND);
        f32x4 v4 = *(const f32x4*)(xp + (size_t)(i + 4) * ND);
        f32x4 v5 = *(const f32x4*)(xp + (size_t)(i + 5) * ND);
        f32x4 v6 = *(const f32x4*)(xp + (size_t)(i + 6) * ND);
        f32x4 v7 = *(const f32x4*)(xp + (size_t)(i + 7) * ND);
        a0 += v0; a1 += v1; a2 += v2; a3 += v3;
        a4 += v4; a5 += v5; a6 += v6; a7 += v7;
    }
    f32x4 acc = ((a0 + a1) + (a2 + a3)) + ((a4 + a5) + (a6 + a7));
    *(f32x4*)(partial + ((size_t)(b * SPLIT + s)) * ND + d4) = acc;
}

// ---------------- k1b: WIDE reduce partial[b][s][D] -> h[b][D] (1/NL scaled).
// 16 blocks x 256 threads = 4096 threads, one f32x4 each; 4 MB coalesced.
__global__ __launch_bounds__(256) void k1b_reduce(const float* __restrict__ partial,
                                                  float* __restrict__ h) {
    int t = blockIdx.x * 256 + threadIdx.x;       // 0..4095 over B*D/4
    int b = t >> 9;                               // /512 (ND/4=512 f32x4 per b)
    int d4 = t & 511;
    const float* pb = partial + (size_t)b * SPLIT * ND + d4 * 4;
    f32x4 s0 = {0.f, 0.f, 0.f, 0.f}, s1 = s0, s2 = s0, s3 = s0;
#pragma unroll 4
    for (int s = 0; s < SPLIT; s += 4) {
        s0 += *(const f32x4*)(pb + (size_t)(s + 0) * ND);
        s1 += *(const f32x4*)(pb + (size_t)(s + 1) * ND);
        s2 += *(const f32x4*)(pb + (size_t)(s + 2) * ND);
        s3 += *(const f32x4*)(pb + (size_t)(s + 3) * ND);
    }
    f32x4 r = ((s0 + s1) + (s2 + s3)) * (1.0f / NL);
    *(f32x4*)(h + (size_t)b * ND + d4 * 4) = r;
}

// ---------------- kB: router logits, top-2, LoRA delta (one block per b).
// h read from global (64 KB, L2-warm from k1b).
__global__ __launch_bounds__(256) void kB_router(const float* __restrict__ hbuf,
                                                 const float* __restrict__ gate_w,
                                                 const float* __restrict__ gate_b,
                                                 const float* __restrict__ A,
                                                 const float* __restrict__ Bw,
                                                 float* __restrict__ delta,
                                                 float* __restrict__ logits_out,
                                                 int* __restrict__ idx_out) {
    __shared__ float sh_h[ND];
    __shared__ float sh_logits[NE];
    __shared__ float sh_t[KTOP * NR];
    __shared__ float sh_w[KTOP];
    __shared__ int sh_idx[KTOP];
    int b = blockIdx.x;
    int tid = threadIdx.x;

    {
        int d4 = tid * 8;
        f32x4 v0 = *(const f32x4*)(hbuf + (size_t)b * ND + d4);
        f32x4 v1 = *(const f32x4*)(hbuf + (size_t)b * ND + d4 + 4);
        *(f32x4*)(sh_h + d4) = v0;
        *(f32x4*)(sh_h + d4 + 4) = v1;
    }
    __syncthreads();

    {
        int e = tid >> 5, lane32 = tid & 31;
        const f32x4* gw = (const f32x4*)(gate_w + (size_t)e * ND);
        float p = 0.f;
#pragma unroll 4
        for (int d4 = lane32; d4 < ND / 4; d4 += 32) {
            f32x4 gv = gw[d4];
            f32x4 hv = *(const f32x4*)(sh_h + d4 * 4);
            p += gv.x * hv.x + gv.y * hv.y + gv.z * hv.z + gv.w * hv.w;
        }
        for (int off = 16; off; off >>= 1) p += __shfl_down(p, off);
        if (lane32 == 0) sh_logits[e] = p + gate_b[e];
    }
    __syncthreads();

    if (tid == 0) {
        float v1 = -1e30f; int e1 = 0;
        for (int e = 0; e < NE; ++e) if (sh_logits[e] > v1) { v1 = sh_logits[e]; e1 = e; }
        float v2 = -1e30f; int e2 = 0;
        for (int e = 0; e < NE; ++e) if (e != e1 && sh_logits[e] > v2) { v2 = sh_logits[e]; e2 = e; }
        float ex = expf(v2 - v1);
        float w1 = 1.0f / (1.0f + ex);
        sh_idx[0] = e1; sh_idx[1] = e2;
        sh_w[0] = w1; sh_w[1] = ex * w1;
        idx_out[b * KTOP] = e1; idx_out[b * KTOP + 1] = e2;
        for (int e = 0; e < NE; ++e) logits_out[b * NE + e] = sh_logits[e];
    }
    __syncthreads();

    {
        int grp = tid >> 4, lane16 = tid & 15;
        int k = grp >> 3, r = grp & 7;
        int e = sh_idx[k];
        const f32x4* ap = (const f32x4*)(A + ((size_t)e * NR + r) * ND);
        float p = 0.f;
#pragma unroll 4
        for (int d4 = lane16; d4 < ND / 4; d4 += 16) {
            f32x4 av = ap[d4];
            f32x4 hv = *(const f32x4*)(sh_h + d4 * 4);
            p += av.x * hv.x + av.y * hv.y + av.z * hv.z + av.w * hv.w;
        }
        for (int off = 8; off; off >>= 1) p += __shfl_down(p, off);
        if (lane16 == 0) sh_t[grp] = p;
    }
    __syncthreads();

    for (int dd = tid; dd < ND; dd += 256) {
        float acc = 0.f;
#pragma unroll
        for (int k = 0; k < KTOP; ++k) {
            int e = sh_idx[k];
            const f32x4* bw = (const f32x4*)(Bw + ((size_t)e * ND + dd) * NR);
            f32x4 w0 = bw[0], w1 = bw[1];
            float s = sh_t[k * NR + 0] * w0.x + sh_t[k * NR + 1] * w0.y +
                      sh_t[k * NR + 2] * w0.z + sh_t[k * NR + 3] * w0.w +
                      sh_t[k * NR + 4] * w1.x + sh_t[k * NR + 5] * w1.y +
                      sh_t[k * NR + 6] * w1.z + sh_t[k * NR + 7] * w1.w;
            acc += sh_w[k] * s;
        }
        delta[b * ND + dd] = acc * ALPHA;
    }
}

// ---------------- k4: residual + LayerNorm. ONE WAVE = TWO ROWS (row, row+16384).
// BEST-KNOWN CELL (R7): NORMAL x loads + NT y stores (A/B matrix R7/R9/R10/R11:
// NT store is worth ~37us -- y write-allocation thrashes the x read stream;
// NT loads cost ~4-15us -- lose L2 sector coalescing). aux fold kept (harmless).
__global__ __launch_bounds__(256) void k4_ln(const float* __restrict__ x,
                                             const float* __restrict__ delta,
                                             const float* __restrict__ gamma,
                                             const float* __restrict__ beta,
                                             const float* __restrict__ logits,
                                             const int* __restrict__ idxp,
                                             float* __restrict__ y,
                                             float* __restrict__ aux_out) {
    int wave = blockIdx.x * 4 + (threadIdx.x >> 6);   // 0..16383
    int lane = threadIdx.x & 63;
    size_t ra = (size_t)wave * ND;
    size_t rb = ((size_t)wave + 16384) * ND;
    int ba = wave >> 12;            // 0..3
    int bb = ba + 4;

    const f32x4* xa = (const f32x4*)(x + ra);
    const f32x4* xb = (const f32x4*)(x + rb);
    const f32x4* da = (const f32x4*)(delta + (size_t)ba * ND);
    const f32x4* db = (const f32x4*)(delta + (size_t)bb * ND);

    f32x4 va[8], vb[8];
#pragma unroll
    for (int j = 0; j < 8; ++j) va[j] = xa[lane + 64 * j];
#pragma unroll
    for (int j = 0; j < 8; ++j) vb[j] = xb[lane + 64 * j];
#pragma unroll
    for (int j = 0; j < 8; ++j) va[j] += da[lane + 64 * j];
#pragma unroll
    for (int j = 0; j < 8; ++j) vb[j] += db[lane + 64 * j];

    float sa = 0.f, ssa = 0.f, sb = 0.f, ssb = 0.f;
#pragma unroll
    for (int j = 0; j < 8; ++j) {
        sa  += va[j].x + va[j].y + va[j].z + va[j].w;
        ssa += va[j].x * va[j].x + va[j].y * va[j].y + va[j].z * va[j].z + va[j].w * va[j].w;
        sb  += vb[j].x + vb[j].y + vb[j].z + vb[j].w;
        ssb += vb[j].x * vb[j].x + vb[j].y * vb[j].y + vb[j].z * vb[j].z + vb[j].w * vb[j].w;
    }
    for (int off = 32; off; off >>= 1) {
        sa  += __shfl_xor(sa, off);
        ssa += __shfl_xor(ssa, off);
        sb  += __shfl_xor(sb, off);
        ssb += __shfl_xor(ssb, off);
    }
    float mua = sa * (1.0f / ND);
    float rsa = rsqrtf(ssa * (1.0f / ND) - mua * mua + LN_EPS);
    float mub = sb * (1.0f / ND);
    float rsb = rsqrtf(ssb * (1.0f / ND) - mub * mub + LN_EPS);

    f32x4* ya = (f32x4*)(y + ra);
    f32x4* yb = (f32x4*)(y + rb);
#pragma unroll
    for (int j = 0; j < 8; ++j) {
        f32x4 gv = *(const f32x4*)(gamma + (lane + 64 * j) * 4);
        f32x4 bv = *(const f32x4*)(beta  + (lane + 64 * j) * 4);
        f32x4 oa = (va[j] - mua) * rsa * gv + bv;
        f32x4 ob = (vb[j] - mub) * rsb * gv + bv;
        __builtin_nontemporal_store(oa, ya + lane + 64 * j);
        __builtin_nontemporal_store(ob, yb + lane + 64 * j);
    }

    // ---- aux losses (one scalar lane) ----
    if (blockIdx.x == 0 && threadIdx.x == 0) {
        float counts[NE];
        for (int e = 0; e < NE; ++e) counts[e] = 0.f;
        for (int i = 0; i < NB * KTOP; ++i) counts[idxp[i]] += 1.f;
        float f[NE], P[NE];
        for (int e = 0; e < NE; ++e) { f[e] = counts[e] * (1.0f / (NB * KTOP)); P[e] = 0.f; }
        float z = 0.f;
        for (int bq = 0; bq < NB; ++bq) {
            const float* lg = logits + bq * NE;
            float m = lg[0];
            for (int e = 1; e < NE; ++e) m = fmaxf(m, lg[e]);
            float sum = 0.f;
            for (int e = 0; e < NE; ++e) sum += expf(lg[e] - m);
            float inv = 1.0f / sum;
            for (int e = 0; e < NE; ++e) P[e] += expf(lg[e] - m) * inv;
            float lse = m + logf(sum);
            z += lse * lse;
        }
        z *= (1.0f / NB);
        float lb = 0.f;
        for (int e = 0; e < NE; ++e) lb += f[e] * (P[e] * (1.0f / NB));
        lb *= (float)NE;
        float psum = 0.f;
        for (int e = 0; e < NE; ++e) psum += f[e] + 1e-8f;
        float s2 = 0.f;
        for (int e = 0; e < NE; ++e) { float p = (f[e] + 1e-8f) / psum; s2 += p * p; }
        aux_out[0] = 0.01f * lb + 0.001f * z + 0.01f * logf(s2);
    }
}

extern "C" void kernel_launch(void* const* d_in, const int* in_sizes, int n_in,
                              void* d_out, int out_size, void* d_ws, size_t ws_size,
                              hipStream_t stream) {
    const float* x      = (const float*)d_in[0];
    const float* gate_w = (const float*)d_in[1];
    const float* gate_b = (const float*)d_in[2];
    const float* A      = (const float*)d_in[3];
    const float* Bw     = (const float*)d_in[4];
    const float* gamma  = (const float*)d_in[5];
    const float* beta   = (const float*)d_in[6];
    float* y   = (float*)d_out;
    float* aux = y + (size_t)NB * NL * ND;

    // workspace: partial[B][SPLIT][D] | h[B][D] | delta[B][D] | logits[B][E] | idx
    float* partial = (float*)d_ws;
    float* hbuf    = partial + (size_t)NB * SPLIT * ND;
    float* delta   = hbuf + NB * ND;
    float* logits  = delta + NB * ND;
    int*   idxp    = (int*)(logits + NB * NE);

    hipLaunchKernelGGL(k1_partial_mean, dim3(SPLIT * NB * 2), dim3(256), 0, stream,
                       x, partial);
    hipLaunchKernelGGL(k1b_reduce, dim3(16), dim3(256), 0, stream,
                       partial, hbuf);
    hipLaunchKernelGGL(kB_router, dim3(NB), dim3(256), 0, stream,
                       hbuf, gate_w, gate_b, A, Bw, delta, logits, idxp);
    hipLaunchKernelGGL(k4_ln, dim3(4096), dim3(256), 0, stream,
                       x, delta, gamma, beta, logits, idxp, y, aux);
}